// Round 3
// baseline (463.389 us; speedup 1.0000x reference)
//
#include <hip/hip_runtime.h>
#include <hip/hip_cooperative_groups.h>
#include <cmath>

namespace cg = cooperative_groups;

#define NB 8
#define NA 49104
#define NM 50
#define NC 90
#define NBX 128   // blocks per sample; each handles APB anchors
#define APB 384   // 128*384 = 49152 >= 49104

// ws layout (floats):
//   [0          .. NB*NBX)    cls partials (neg sum + pos correction)
//   [NB*NBX     .. 2*NB*NBX)  reg partials
//   [2*NB*NBX   .. 3*NB*NBX)  num_pos partials
// All slots overwritten every launch (no init, no atomics).

__device__ __forceinline__ float clipc(float x) {
    return fminf(fmaxf(x, 1e-4f), 1.0f - 1e-4f);
}

__device__ __forceinline__ float negterm(float x) {
    const float c = clipc(x);
    return 0.75f * c * c * (-__logf(1.0f - c));
}

// Block reduction: wave64 shuffle then LDS across waves. Valid on tid 0.
__device__ __forceinline__ float block_reduce(float v, float* red) {
#pragma unroll
    for (int o = 32; o > 0; o >>= 1) v += __shfl_down(v, o, 64);
    const int wave = threadIdx.x >> 6;
    const int lane = threadIdx.x & 63;
    if (lane == 0) red[wave] = v;
    __syncthreads();
    float r = 0.f;
    if (threadIdx.x == 0) {
        const int nw = blockDim.x >> 6;
        for (int w = 0; w < nw; ++w) r += red[w];
    }
    __syncthreads();  // allow red reuse by a later call
    return r;
}

// Single cooperative kernel: assignment + smooth-L1 + focal streaming sum
// per block, grid sync, then block (0,0) finalizes the two outputs.
__global__ __launch_bounds__(256, 4) void fused_kernel(
    const float* __restrict__ boxes,      // [B,M,4] x1y1x2y2
    const int*   __restrict__ labels,     // [B,M], 0 = padding
    const float* __restrict__ regression, // [B,A,4]
    const float* __restrict__ cls,        // [B,A,C]
    const float* __restrict__ anchors,    // [A,4] y1x1y2x2
    float* __restrict__ ws,
    float* __restrict__ out) {
    __shared__ float4 sbox[NM];
    __shared__ float  sarea[NM];
    __shared__ int    slab[NM];
    __shared__ float  red[4];

    const int b  = blockIdx.y;
    const int t  = threadIdx.x;
    const int a0 = blockIdx.x * APB;
    const int aend = (a0 + APB < NA) ? a0 + APB : NA;

    if (t < NM) {
        float4 bx = ((const float4*)boxes)[b * NM + t];
        const int l = labels[b * NM + t];
        float area = (bx.z - bx.x) * (bx.w - bx.y);
        if (l == 0) {
            // Invalid box: degenerate coords force inter=0 -> iou=0.
            // Output-equivalent to the reference's -1 mask (0 < 0.15 so
            // pos=false; ties at 0 only matter when !pos, where alab and
            // assigned are unused).
            bx.x = bx.y = bx.z = bx.w = 3e38f;
            area = 0.f;
        }
        sbox[t]  = bx;
        sarea[t] = area;
        slab[t]  = (l != 0) ? (l - 1) : 0;
    }
    __syncthreads();

    float corr = 0.f, regs = 0.f, npos = 0.f;
    for (int a = a0 + t; a < aend; a += 256) {
        const float4 an = ((const float4*)anchors)[a];
        const float ay1 = an.x, ax1 = an.y, ay2 = an.z, ax2 = an.w;
        const float aarea = (ay2 - ay1) * (ax2 - ax1);

        float best = -1.f;
        int arg = 0;
        for (int m = 0; m < NM; ++m) {
            const float4 bx = sbox[m];  // broadcast, conflict-free
            float iw = fminf(ax2, bx.z) - fmaxf(ax1, bx.x);
            float ih = fminf(ay2, bx.w) - fmaxf(ay1, bx.y);
            iw = fmaxf(iw, 0.f);
            ih = fmaxf(ih, 0.f);
            const float inter = iw * ih;
            const float ua = fmaxf(aarea + sarea[m] - inter, 1e-8f);
            const float iou = inter / ua;
            if (iou > best) { best = iou; arg = m; }  // first-occurrence
        }

        const bool big = sarea[arg] > 100.0f;
        const bool pos = big ? (best >= 0.5f) : (best >= 0.15f);
        if (pos) {
            npos += 1.f;
            const float4 bx = sbox[arg];
            const float aw = ax2 - ax1, ah = ay2 - ay1;
            const float acx = ax1 + 0.5f * aw, acy = ay1 + 0.5f * ah;
            const float gw0 = bx.z - bx.x, gh0 = bx.w - bx.y;
            const float gcx = bx.x + 0.5f * gw0, gcy = bx.y + 0.5f * gh0;
            const float gw = fmaxf(gw0, 1.f), gh = fmaxf(gh0, 1.f);
            const float4 r = ((const float4*)regression)[b * NA + a];
            const float d0 = fabsf((gcy - acy) / ah - r.x);
            const float d1 = fabsf((gcx - acx) / aw - r.y);
            const float d2 = fabsf(__logf(gh / ah) - r.z);
            const float d3 = fabsf(__logf(gw / aw) - r.w);
            regs += (d0 <= 1.f / 9.f) ? 4.5f * d0 * d0 : d0 - (0.5f / 9.f);
            regs += (d1 <= 1.f / 9.f) ? 4.5f * d1 * d1 : d1 - (0.5f / 9.f);
            regs += (d2 <= 1.f / 9.f) ? 4.5f * d2 * d2 : d2 - (0.5f / 9.f);
            regs += (d3 <= 1.f / 9.f) ? 4.5f * d3 * d3 : d3 - (0.5f / 9.f);

            // replace neg term with pos term at (a, alab)
            const int alab = slab[arg];
            const float c = clipc(cls[((size_t)b * NA + a) * NC + alab]);
            const float omc = 1.f - c;
            corr += 0.25f * omc * omc * (-__logf(c)) -
                    0.75f * c * c * (-__logf(omc));
        }
    }

    // Streaming negative-term sum over this block's contiguous cls slice.
    // (aend-a0)*NC is divisible by 4 (384*90, 336*90); base offsets too.
    const int n4 = ((aend - a0) * NC) >> 2;
    const float4* p = (const float4*)(cls + ((size_t)b * NA + a0) * NC);
    float neg = 0.f;
    for (int i = t; i < n4; i += 256) {
        const float4 v = p[i];
        neg += negterm(v.x) + negterm(v.y) + negterm(v.z) + negterm(v.w);
    }

    const float tc = block_reduce(neg + corr, red);
    const float tr = block_reduce(regs, red);
    const float tn = block_reduce(npos, red);
    if (t == 0) {
        const int idx = b * NBX + blockIdx.x;
        ws[idx]                = tc;
        ws[NB * NBX + idx]     = tr;
        ws[2 * NB * NBX + idx] = tn;
    }
    __threadfence();  // device-scope release of partials

    cg::this_grid().sync();

    // Finalize on block (0,0) only.
    if (blockIdx.x != 0 || blockIdx.y != 0) return;
    float cl = 0.f, rl = 0.f;
    for (int bb = 0; bb < NB; ++bb) {
        const float vc = (t < NBX) ? ws[bb * NBX + t] : 0.f;
        const float vr = (t < NBX) ? ws[NB * NBX + bb * NBX + t] : 0.f;
        const float vn = (t < NBX) ? ws[2 * NB * NBX + bb * NBX + t] : 0.f;
        const float sc = block_reduce(vc, red);
        const float sr = block_reduce(vr, red);
        const float sn = block_reduce(vn, red);
        if (t == 0) {
            cl += sc / fmaxf(sn, 1.f);
            rl += (sn > 0.f) ? sr / (sn * 4.f) : 0.f;
        }
    }
    if (t == 0) {
        out[0] = cl / (float)NB;
        out[1] = rl / (float)NB * 50.f;
    }
}

extern "C" void kernel_launch(void* const* d_in, const int* in_sizes, int n_in,
                              void* d_out, int out_size, void* d_ws,
                              size_t ws_size, hipStream_t stream) {
    const float* boxes      = (const float*)d_in[0];  // [B,M,4] f32
    const int*   labels     = (const int*)d_in[1];    // [B,M] i32
    const float* regression = (const float*)d_in[2];  // [B,A,4] f32
    const float* cls        = (const float*)d_in[3];  // [B,A,C] f32
    const float* anchors    = (const float*)d_in[4];  // [1,A,4] f32
    float* out = (float*)d_out;
    float* ws  = (float*)d_ws;

    void* args[] = {(void*)&boxes, (void*)&labels, (void*)&regression,
                    (void*)&cls,   (void*)&anchors, (void*)&ws, (void*)&out};
    // 1024 blocks = 4 blocks/CU (co-resident: __launch_bounds__(256,4)
    // caps VGPR at 128; 1.2 KB LDS; 1024 <= 256 CU * 4).
    hipLaunchCooperativeKernel((const void*)fused_kernel,
                               dim3(NBX, NB), dim3(256), args, 0, stream);
}

// Round 4
// 302.648 us; speedup vs baseline: 1.5311x; 1.5311x over previous
//
#include <hip/hip_runtime.h>
#include <cmath>

#define NB 8
#define NA 49104
#define NM 50
#define NC 90
#define NBLK 192                 // blocks per sample (x-dim)
#define NBLOCKS (NB * NBLK)      // 1536 total

// ws layout (floats):
//   [0            .. NB*NBLK)    cls partials (neg sum + pos correction)
//   [NB*NBLK      .. 2*NB*NBLK)  reg partials
//   [2*NB*NBLK    .. 3*NB*NBLK)  num_pos partials
//   [3*NB*NBLK]                  completion counter (uint, memset to 0)
// Partials are overwritten every launch; only the counter needs init.

__device__ __forceinline__ float clipc(float x) {
    return fminf(fmaxf(x, 1e-4f), 1.0f - 1e-4f);
}

__device__ __forceinline__ float negterm(float x) {
    const float c = clipc(x);
    return 0.75f * c * c * (-__logf(1.0f - c));
}

// Block reduction: wave64 shuffle then LDS across waves. Valid on tid 0.
__device__ __forceinline__ float block_reduce(float v, float* red) {
#pragma unroll
    for (int o = 32; o > 0; o >>= 1) v += __shfl_down(v, o, 64);
    const int wave = threadIdx.x >> 6;
    const int lane = threadIdx.x & 63;
    if (lane == 0) red[wave] = v;
    __syncthreads();
    float r = 0.f;
    if (threadIdx.x == 0) {
        const int nw = blockDim.x >> 6;
        for (int w = 0; w < nw; ++w) r += red[w];
    }
    __syncthreads();  // allow red reuse by a later call
    return r;
}

// One block = 256 consecutive anchors of one sample: assignment + smooth-L1
// + streaming focal sum over the block's own contiguous cls slice. The last
// block to finish (atomic counter) finalizes the two outputs inline —
// no grid barrier, no second dispatch.
__global__ __launch_bounds__(256) void fused_kernel(
    const float* __restrict__ boxes,      // [B,M,4] x1y1x2y2
    const int*   __restrict__ labels,     // [B,M], 0 = padding
    const float* __restrict__ regression, // [B,A,4]
    const float* __restrict__ cls,        // [B,A,C]
    const float* __restrict__ anchors,    // [A,4] y1x1y2x2
    float* __restrict__ ws,
    float* __restrict__ out) {
    __shared__ float4 sbox[NM];
    __shared__ float  sarea[NM];
    __shared__ int    slab[NM];
    __shared__ float  red[4];
    __shared__ int    is_last;

    const int b  = blockIdx.y;
    const int t  = threadIdx.x;
    const int a0 = blockIdx.x << 8;

    if (t < NM) {
        float4 bx = ((const float4*)boxes)[b * NM + t];
        const int l = labels[b * NM + t];
        float area = (bx.z - bx.x) * (bx.w - bx.y);
        if (l == 0) {
            // Invalid box: degenerate coords force inter=0 -> iou=0.
            // Output-equivalent to the reference's -1 mask (0 < 0.15 so
            // pos=false; ties at 0 only matter when !pos, where alab and
            // assigned are unused).
            bx.x = bx.y = bx.z = bx.w = 3e38f;
            area = 0.f;
        }
        sbox[t]  = bx;
        sarea[t] = area;
        slab[t]  = (l != 0) ? (l - 1) : 0;
    }
    __syncthreads();

    float corr = 0.f, regs = 0.f, npos = 0.f;
    const int a = a0 + t;
    if (a < NA) {
        const float4 an = ((const float4*)anchors)[a];
        const float ay1 = an.x, ax1 = an.y, ay2 = an.z, ax2 = an.w;
        const float aarea = (ay2 - ay1) * (ax2 - ax1);

        float best = -1.f;
        int arg = 0;
        for (int m = 0; m < NM; ++m) {
            const float4 bx = sbox[m];  // broadcast, conflict-free
            float iw = fminf(ax2, bx.z) - fmaxf(ax1, bx.x);
            float ih = fminf(ay2, bx.w) - fmaxf(ay1, bx.y);
            iw = fmaxf(iw, 0.f);
            ih = fmaxf(ih, 0.f);
            const float inter = iw * ih;
            const float ua = fmaxf(aarea + sarea[m] - inter, 1e-8f);
            const float iou = inter / ua;
            if (iou > best) { best = iou; arg = m; }  // first-occurrence
        }

        const bool big = sarea[arg] > 100.0f;
        const bool pos = big ? (best >= 0.5f) : (best >= 0.15f);
        if (pos) {
            npos = 1.f;
            const float4 bx = sbox[arg];
            const float aw = ax2 - ax1, ah = ay2 - ay1;
            const float acx = ax1 + 0.5f * aw, acy = ay1 + 0.5f * ah;
            const float gw0 = bx.z - bx.x, gh0 = bx.w - bx.y;
            const float gcx = bx.x + 0.5f * gw0, gcy = bx.y + 0.5f * gh0;
            const float gw = fmaxf(gw0, 1.f), gh = fmaxf(gh0, 1.f);
            const float4 r = ((const float4*)regression)[b * NA + a];
            const float d0 = fabsf((gcy - acy) / ah - r.x);
            const float d1 = fabsf((gcx - acx) / aw - r.y);
            const float d2 = fabsf(__logf(gh / ah) - r.z);
            const float d3 = fabsf(__logf(gw / aw) - r.w);
            regs  = (d0 <= 1.f / 9.f) ? 4.5f * d0 * d0 : d0 - (0.5f / 9.f);
            regs += (d1 <= 1.f / 9.f) ? 4.5f * d1 * d1 : d1 - (0.5f / 9.f);
            regs += (d2 <= 1.f / 9.f) ? 4.5f * d2 * d2 : d2 - (0.5f / 9.f);
            regs += (d3 <= 1.f / 9.f) ? 4.5f * d3 * d3 : d3 - (0.5f / 9.f);

            // replace neg term with pos term at (a, alab)
            const int alab = slab[arg];
            const float c = clipc(cls[((size_t)b * NA + a) * NC + alab]);
            const float omc = 1.f - c;
            corr = 0.25f * omc * omc * (-__logf(c)) -
                   0.75f * c * c * (-__logf(omc));
        }
    }

    // Streaming negative-term sum over this block's contiguous cls slice:
    // anchors [a0, aend) x 90 classes; lengths/offsets all float4-aligned.
    const int aend = (a0 + 256 < NA) ? a0 + 256 : NA;
    const int n4 = ((aend - a0) * NC) >> 2;
    const float4* p = (const float4*)(cls + ((size_t)b * NA + a0) * NC);
    float neg = 0.f;
    for (int i = t; i < n4; i += 256) {
        const float4 v = p[i];
        neg += negterm(v.x) + negterm(v.y) + negterm(v.z) + negterm(v.w);
    }

    const float tc = block_reduce(neg + corr, red);
    const float tr = block_reduce(regs, red);
    const float tn = block_reduce(npos, red);
    unsigned int* counter = (unsigned int*)(ws + 3 * NBLOCKS);
    if (t == 0) {
        const int idx = b * NBLK + blockIdx.x;
        ws[idx]               = tc;
        ws[NBLOCKS + idx]     = tr;
        ws[2 * NBLOCKS + idx] = tn;
        __threadfence();  // device-scope release of this block's partials
        const unsigned int prev = atomicAdd(counter, 1u);
        is_last = (prev == NBLOCKS - 1) ? 1 : 0;
    }
    __syncthreads();
    if (!is_last) return;

    // Last-finishing block: acquire, then finalize inline.
    __threadfence();
    float cl = 0.f, rl = 0.f;
    for (int bb = 0; bb < NB; ++bb) {
        const float vc = (t < NBLK) ? ws[bb * NBLK + t] : 0.f;
        const float vr = (t < NBLK) ? ws[NBLOCKS + bb * NBLK + t] : 0.f;
        const float vn = (t < NBLK) ? ws[2 * NBLOCKS + bb * NBLK + t] : 0.f;
        const float sc = block_reduce(vc, red);
        const float sr = block_reduce(vr, red);
        const float sn = block_reduce(vn, red);
        if (t == 0) {
            cl += sc / fmaxf(sn, 1.f);
            rl += (sn > 0.f) ? sr / (sn * 4.f) : 0.f;
        }
    }
    if (t == 0) {
        out[0] = cl / (float)NB;
        out[1] = rl / (float)NB * 50.f;
    }
}

extern "C" void kernel_launch(void* const* d_in, const int* in_sizes, int n_in,
                              void* d_out, int out_size, void* d_ws,
                              size_t ws_size, hipStream_t stream) {
    const float* boxes      = (const float*)d_in[0];  // [B,M,4] f32
    const int*   labels     = (const int*)d_in[1];    // [B,M] i32
    const float* regression = (const float*)d_in[2];  // [B,A,4] f32
    const float* cls        = (const float*)d_in[3];  // [B,A,C] f32
    const float* anchors    = (const float*)d_in[4];  // [1,A,4] f32
    float* out = (float*)d_out;
    float* ws  = (float*)d_ws;

    // Zero only the 4-byte completion counter (robust to ws poison).
    hipMemsetAsync(ws + 3 * NBLOCKS, 0, sizeof(unsigned int), stream);

    dim3 g(NBLK, NB);  // 1536 blocks, 6/CU
    fused_kernel<<<g, 256, 0, stream>>>(boxes, labels, regression, cls,
                                        anchors, ws, out);
}

// Round 5
// 240.072 us; speedup vs baseline: 1.9302x; 1.2607x over previous
//
#include <hip/hip_runtime.h>
#include <cmath>

#define NB 8
#define NA 49104
#define NM 50
#define NC 90
#define NBLK 192  // ceil(NA/256)

// ws layout (floats):
//   [0             .. NB*NBLK)    cls partials (neg sum + pos correction)
//   [NB*NBLK       .. 2*NB*NBLK)  reg partials
//   [2*NB*NBLK     .. 3*NB*NBLK)  num_pos partials
// All slots overwritten every launch (no init, no atomics, no fences).

__device__ __forceinline__ float clipc(float x) {
    return fminf(fmaxf(x, 1e-4f), 1.0f - 1e-4f);
}

__device__ __forceinline__ float negterm(float x) {
    const float c = clipc(x);
    return 0.75f * c * c * (-__logf(1.0f - c));
}

// Block reduction: wave64 shuffle then LDS across waves. Valid on tid 0.
__device__ __forceinline__ float block_reduce(float v, float* red) {
#pragma unroll
    for (int o = 32; o > 0; o >>= 1) v += __shfl_down(v, o, 64);
    const int wave = threadIdx.x >> 6;
    const int lane = threadIdx.x & 63;
    if (lane == 0) red[wave] = v;
    __syncthreads();
    float r = 0.f;
    if (threadIdx.x == 0) {
        const int nw = blockDim.x >> 6;
        for (int w = 0; w < nw; ++w) r += red[w];
    }
    __syncthreads();  // allow red reuse by a later call
    return r;
}

// One block = 256 consecutive anchors of one sample: assignment + smooth-L1
// + streaming focal sum over the block's own contiguous cls slice.
// Streaming loop is unrolled x4 with independent loads for MLP (the R2
// version kept only one float4 in flight -> latency-bound at ~3.5x the
// BW floor).
__global__ __launch_bounds__(256) void fused_kernel(
    const float* __restrict__ boxes,      // [B,M,4] x1y1x2y2
    const int*   __restrict__ labels,     // [B,M], 0 = padding
    const float* __restrict__ regression, // [B,A,4]
    const float* __restrict__ cls,        // [B,A,C]
    const float* __restrict__ anchors,    // [A,4] y1x1y2x2
    float* __restrict__ ws) {
    __shared__ float4 sbox[NM];
    __shared__ float  sarea[NM];
    __shared__ int    slab[NM];
    __shared__ float  red[4];

    const int b  = blockIdx.y;
    const int t  = threadIdx.x;
    const int a0 = blockIdx.x << 8;

    if (t < NM) {
        float4 bx = ((const float4*)boxes)[b * NM + t];
        const int l = labels[b * NM + t];
        float area = (bx.z - bx.x) * (bx.w - bx.y);
        if (l == 0) {
            // Invalid box: degenerate coords force inter=0 -> iou=0.
            // Output-equivalent to the reference's -1 mask (0 < 0.15 so
            // pos=false; ties at 0 only matter when !pos, where alab and
            // assigned are unused).
            bx.x = bx.y = bx.z = bx.w = 3e38f;
            area = 0.f;
        }
        sbox[t]  = bx;
        sarea[t] = area;
        slab[t]  = (l != 0) ? (l - 1) : 0;
    }
    __syncthreads();

    // ---- Streaming negative-term sum FIRST (get loads in flight early) ----
    const int aend = (a0 + 256 < NA) ? a0 + 256 : NA;
    const int n4 = ((aend - a0) * NC) >> 2;  // 5760 (full) / 4680 (last)
    const float4* p = (const float4*)(cls + ((size_t)b * NA + a0) * NC);
    float ng0 = 0.f, ng1 = 0.f, ng2 = 0.f, ng3 = 0.f;
    int i = t;
    for (; i + 768 < n4; i += 1024) {
        const float4 v0 = p[i];
        const float4 v1 = p[i + 256];
        const float4 v2 = p[i + 512];
        const float4 v3 = p[i + 768];
        ng0 += negterm(v0.x) + negterm(v0.y) + negterm(v0.z) + negterm(v0.w);
        ng1 += negterm(v1.x) + negterm(v1.y) + negterm(v1.z) + negterm(v1.w);
        ng2 += negterm(v2.x) + negterm(v2.y) + negterm(v2.z) + negterm(v2.w);
        ng3 += negterm(v3.x) + negterm(v3.y) + negterm(v3.z) + negterm(v3.w);
    }
    for (; i < n4; i += 256) {
        const float4 v = p[i];
        ng0 += negterm(v.x) + negterm(v.y) + negterm(v.z) + negterm(v.w);
    }
    float neg = (ng0 + ng1) + (ng2 + ng3);

    // ---- Per-anchor assignment + smooth-L1 + positive correction ----
    float corr = 0.f, regs = 0.f, npos = 0.f;
    const int a = a0 + t;
    if (a < NA) {
        const float4 an = ((const float4*)anchors)[a];
        const float ay1 = an.x, ax1 = an.y, ay2 = an.z, ax2 = an.w;
        const float aarea = (ay2 - ay1) * (ax2 - ax1);

        float best = -1.f;
        int arg = 0;
        for (int m = 0; m < NM; ++m) {
            const float4 bx = sbox[m];  // broadcast, conflict-free
            float iw = fminf(ax2, bx.z) - fmaxf(ax1, bx.x);
            float ih = fminf(ay2, bx.w) - fmaxf(ay1, bx.y);
            iw = fmaxf(iw, 0.f);
            ih = fmaxf(ih, 0.f);
            const float inter = iw * ih;
            const float ua = fmaxf(aarea + sarea[m] - inter, 1e-8f);
            const float iou = inter / ua;
            if (iou > best) { best = iou; arg = m; }  // first-occurrence
        }

        const bool big = sarea[arg] > 100.0f;
        const bool pos = big ? (best >= 0.5f) : (best >= 0.15f);
        if (pos) {
            npos = 1.f;
            const float4 bx = sbox[arg];
            const float aw = ax2 - ax1, ah = ay2 - ay1;
            const float acx = ax1 + 0.5f * aw, acy = ay1 + 0.5f * ah;
            const float gw0 = bx.z - bx.x, gh0 = bx.w - bx.y;
            const float gcx = bx.x + 0.5f * gw0, gcy = bx.y + 0.5f * gh0;
            const float gw = fmaxf(gw0, 1.f), gh = fmaxf(gh0, 1.f);
            const float4 r = ((const float4*)regression)[b * NA + a];
            const float d0 = fabsf((gcy - acy) / ah - r.x);
            const float d1 = fabsf((gcx - acx) / aw - r.y);
            const float d2 = fabsf(__logf(gh / ah) - r.z);
            const float d3 = fabsf(__logf(gw / aw) - r.w);
            regs  = (d0 <= 1.f / 9.f) ? 4.5f * d0 * d0 : d0 - (0.5f / 9.f);
            regs += (d1 <= 1.f / 9.f) ? 4.5f * d1 * d1 : d1 - (0.5f / 9.f);
            regs += (d2 <= 1.f / 9.f) ? 4.5f * d2 * d2 : d2 - (0.5f / 9.f);
            regs += (d3 <= 1.f / 9.f) ? 4.5f * d3 * d3 : d3 - (0.5f / 9.f);

            // replace neg term with pos term at (a, alab)
            const int alab = slab[arg];
            const float c = clipc(cls[((size_t)b * NA + a) * NC + alab]);
            const float omc = 1.f - c;
            corr = 0.25f * omc * omc * (-__logf(c)) -
                   0.75f * c * c * (-__logf(omc));
        }
    }

    const float tc = block_reduce(neg + corr, red);
    const float tr = block_reduce(regs, red);
    const float tn = block_reduce(npos, red);
    if (t == 0) {
        const int idx = b * NBLK + blockIdx.x;
        ws[idx]                 = tc;
        ws[NB * NBLK + idx]     = tr;
        ws[2 * NB * NBLK + idx] = tn;
    }
}

__global__ __launch_bounds__(256) void finalize_kernel(
    const float* __restrict__ ws, float* __restrict__ out) {
    __shared__ float red[4];
    const int t = threadIdx.x;
    float cl = 0.f, rl = 0.f;
    for (int b = 0; b < NB; ++b) {
        const float vc = (t < NBLK) ? ws[b * NBLK + t] : 0.f;
        const float vr = (t < NBLK) ? ws[NB * NBLK + b * NBLK + t] : 0.f;
        const float vn = (t < NBLK) ? ws[2 * NB * NBLK + b * NBLK + t] : 0.f;
        const float sc = block_reduce(vc, red);
        const float sr = block_reduce(vr, red);
        const float sn = block_reduce(vn, red);
        if (t == 0) {
            cl += sc / fmaxf(sn, 1.f);
            rl += (sn > 0.f) ? sr / (sn * 4.f) : 0.f;
        }
    }
    if (t == 0) {
        out[0] = cl / (float)NB;
        out[1] = rl / (float)NB * 50.f;
    }
}

extern "C" void kernel_launch(void* const* d_in, const int* in_sizes, int n_in,
                              void* d_out, int out_size, void* d_ws,
                              size_t ws_size, hipStream_t stream) {
    const float* boxes      = (const float*)d_in[0];  // [B,M,4] f32
    const int*   labels     = (const int*)d_in[1];    // [B,M] i32
    const float* regression = (const float*)d_in[2];  // [B,A,4] f32
    const float* cls        = (const float*)d_in[3];  // [B,A,C] f32
    const float* anchors    = (const float*)d_in[4];  // [1,A,4] f32
    float* out = (float*)d_out;
    float* ws  = (float*)d_ws;

    dim3 g(NBLK, NB);  // 1536 blocks, 6/CU
    fused_kernel<<<g, 256, 0, stream>>>(boxes, labels, regression, cls,
                                        anchors, ws);
    finalize_kernel<<<1, 256, 0, stream>>>(ws, out);
}